// Round 9
// baseline (69.906 us; speedup 1.0000x reference)
//
#include <hip/hip_runtime.h>
#include <hip/hip_bf16.h>
#include <math.h>

// Problem constants (fixed by setup_inputs)
#define NB 16
#define NT 4096
#define NC 64
#define NS 5
#define NH 32

#define TTILE 64
#define RMX 56
#define PN (TTILE + 2*RMX)   // 176 staged t-positions per tile

// tap table segment offsets: radii {10,16,24,36,56} -> lengths {21,33,49,73,113}
#define OFF0 0
#define OFF1 21
#define OFF2 54
#define OFF3 103
#define OFF4 176
#define NTAPS 289

#define NFRAG 13            // K-steps total: 2+2+2+3+4
#define SXT_LD 184          // bf16 elements per channel row
#define SXS_LD 20           // f32 stride for stats rows
#define SXS_ROWS 79         // rows t0-15 .. t0+63

// MLP weight-table (z, logvar) -> 4 softmax weights (5th = 1 - sum)
// layout: [vi][zi], cell = 16B {w0..3 fp16 @ (zi,vi) | w0..3 fp16 @ (zi,vi+1)}
#define NZ 512
#define NV 256
#define ZMINF (-4.0f)
#define VMINF (-14.0f)
#define ZSCLF (511.0f / 8.0f)
#define VSCLF (255.0f / 18.0f)
#define FRAG_BYTES 16384
#define TABLE_BYTES ((size_t)NZ * NV * 16)
#define WS_NEED (FRAG_BYTES + TABLE_BYTES)

typedef __attribute__((ext_vector_type(8))) short bf16x8;
typedef __attribute__((ext_vector_type(4))) float f32x4;
typedef _Float16 h2v __attribute__((ext_vector_type(2)));

__device__ __forceinline__ unsigned short f2b(float f) {
    unsigned int u = __float_as_uint(f);
    unsigned int r = (u + 0x7fffu + ((u >> 16) & 1u)) >> 16;   // RNE
    return (unsigned short)r;
}
// native packed f32x2 -> bf16x2 (v_cvt_pk_bf16_f32)
__device__ __forceinline__ unsigned int pk2b(float a, float b) {
    union { __hip_bfloat162 h; unsigned int u; } t;
    t.h = __float22bfloat162_rn(float2{a, b});
    return t.u;
}
__device__ __forceinline__ h2v u2h(unsigned int u) {
    union { unsigned int u_; h2v h; } t; t.u_ = u; return t.h;
}
__device__ __forceinline__ unsigned int packh2(float a, float b) {
    union { unsigned int u_; _Float16 h[2]; } t;
    t.h[0] = (_Float16)a; t.h[1] = (_Float16)b; return t.u_;
}

// Abramowitz-Stegun 7.1.26, |err| <= 1.5e-7, branchless, no libm.
__device__ __forceinline__ float fast_erf(float x) {
    const float ax = fabsf(x);
    const float t = __fdividef(1.0f, fmaf(0.3275911f, ax, 1.0f));
    float p = fmaf(t, 1.061405429f, -1.453152027f);
    p = fmaf(t, p, 1.421413741f);
    p = fmaf(t, p, -0.284496736f);
    p = fmaf(t, p, 0.254829592f);
    p *= t;
    const float e = __expf(-ax * ax);
    const float r = fmaf(-p, e, 1.0f);
    return copysignf(r, x);
}

// exact-MLP softmax weights (fast-erf flavor): table build + rare slow path
__device__ __forceinline__ void mlp_w_fast(
    float z, float lv,
    const float* __restrict__ W1, const float* __restrict__ b1,
    const float* __restrict__ W2, const float* __restrict__ b2,
    float* __restrict__ wout)
{
    float l0 = b2[0], l1 = b2[1], l2 = b2[2], l3 = b2[3], l4 = b2[4];
    #pragma unroll 4
    for (int j = 0; j < NH; ++j) {
        const float a = fmaf(z, W1[2 * j], fmaf(lv, W1[2 * j + 1], b1[j]));
        const float g = 0.5f * a * (1.0f + fast_erf(a * 0.70710678118654752f));
        l0 = fmaf(g, W2[j],          l0);
        l1 = fmaf(g, W2[NH + j],     l1);
        l2 = fmaf(g, W2[2 * NH + j], l2);
        l3 = fmaf(g, W2[3 * NH + j], l3);
        l4 = fmaf(g, W2[4 * NH + j], l4);
    }
    const float sc = 1.4285714285714286f;
    const float mx = fmaxf(fmaxf(fmaxf(l0, l1), fmaxf(l2, l3)), l4);
    const float e0 = __expf((l0 - mx) * sc);
    const float e1 = __expf((l1 - mx) * sc);
    const float e2 = __expf((l2 - mx) * sc);
    const float e3 = __expf((l3 - mx) * sc);
    const float e4 = __expf((l4 - mx) * sc);
    const float rd = __fdividef(1.0f, e0 + e1 + e2 + e3 + e4);
    wout[0] = e0 * rd; wout[1] = e1 * rd; wout[2] = e2 * rd;
    wout[3] = e3 * rd; wout[4] = e4 * rd;
}

// ---------------- single init launch: block 0 -> A-frags; blocks 1.. -> LUT ----------------
__global__ void init_all_kernel(
    const float* __restrict__ W1, const float* __restrict__ b1,
    const float* __restrict__ W2, const float* __restrict__ b2,
    unsigned short* __restrict__ afr, unsigned int* __restrict__ tbl, int build_tbl)
{
    const int tid = threadIdx.x;
    if (blockIdx.x == 0) {
        __shared__ float raw[NTAPS];
        __shared__ float invs[NS];
        const int offs[6] = {OFF0, OFF1, OFF2, OFF3, OFF4, NTAPS};
        const float sig[NS] = {2.5f, 4.0f, 6.0f, 9.0f, 14.0f};
        const int RR[NS] = {10, 16, 24, 36, 56};
        for (int i = tid; i < NTAPS; i += blockDim.x) {
            int s = 0;
            #pragma unroll
            for (int k = 1; k < NS; ++k) if (i >= offs[k]) s = k;
            const int j = i - offs[s] - RR[s];
            const float u = (float)j / sig[s];
            raw[i] = __expf(-0.5f * u * u);
        }
        __syncthreads();
        if (tid < NS) {
            float sum = 0.f;
            for (int i = offs[tid]; i < offs[tid + 1]; ++i) sum += raw[i];
            invs[tid] = 1.0f / (sum + 1e-12f);
        }
        __syncthreads();
        const int fbase6[6] = {0, 2, 4, 6, 9, 13};
        const int RA[NS] = {16, 16, 24, 40, 56};
        for (int idx = tid; idx < NFRAG * 64 * 8; idx += blockDim.x) {
            const int f = idx >> 9;
            const int lane = (idx >> 3) & 63;
            const int e = idx & 7;
            int s = 0;
            #pragma unroll
            for (int k = 1; k < NS; ++k) if (f >= fbase6[k]) s = k;
            const int kk = f - fbase6[s];
            const int r = lane & 15;
            const int g = lane >> 4;
            const int j = 32 * kk + 8 * g + e - RA[s] - r;
            float v = 0.f;
            if (j >= -RR[s] && j <= RR[s]) v = raw[offs[s] + j + RR[s]] * invs[s];
            afr[idx] = f2b(v);
        }
    } else if (build_tbl) {
        const int idx = (blockIdx.x - 1) * 256 + tid;   // zi*NV + vi (compute grid)
        const int zi = idx / NV, vi = idx % NV;
        const float z  = ZMINF + (float)zi * (8.0f / 511.0f);
        const float lv = VMINF + (float)vi * (18.0f / 255.0f);
        float w[5];
        mlp_w_fast(z, lv, W1, b1, W2, b2, w);
        const unsigned int p01 = packh2(w[0], w[1]);
        const unsigned int p23 = packh2(w[2], w[3]);
        uint2 p = {p01, p23};
        // storage layout [vi][zi]: cell c(vi,zi) = {w @ (zi,vi) | w @ (zi,vi+1)}
        *reinterpret_cast<uint2*>(tbl + ((size_t)vi * NZ + zi) * 4) = p;          // own lo
        if (vi > 0)
            *reinterpret_cast<uint2*>(tbl + ((size_t)(vi - 1) * NZ + zi) * 4 + 2) = p; // row below's hi
        if (vi == NV - 1)
            *reinterpret_cast<uint2*>(tbl + ((size_t)vi * NZ + zi) * 4 + 2) = p;       // self hi (clamp)
    }
}

// ---------------- fused main kernel ----------------
// grid: 4 cq-planes x (NB * NT/TTILE); block = (cq, b, 64-t tile) = 64 t x 16 c.
// Wave wv: t rows [16wv,16wv+16) x 16 c. Register phases kept disjoint:
// stats -> (gathers+f16 bilerp -> 16 weights) -> MFMA(20 acc) -> blend/store.
template<bool SLOW>
__global__ __launch_bounds__(256, 8) void fused9_kernel(
    const float* __restrict__ x,  const float* __restrict__ W1,
    const float* __restrict__ b1, const float* __restrict__ W2,
    const float* __restrict__ b2, const uint4* __restrict__ afr4,
    const uint4* __restrict__ tb4, float* __restrict__ out)
{
    __shared__ __align__(16) short sxT[16 * SXT_LD];          // bf16 [c][t], 5888 B
    __shared__ __align__(16) float sxS[SXS_ROWS * SXS_LD];    // f32  [t][c], 6320 B

    const int blk = blockIdx.x;
    const int bt = blk & 1023;
    const int cq = blk >> 10;             // slowest dim
    const int b  = bt >> 6;
    const int t0 = (bt & 63) * TTILE;
    const int c0 = cq << 4;
    const float* xb = x + (size_t)b * NT * NC;
    const int tid = threadIdx.x;

    // ---- stage sxT (bf16 [c][t], reflect-padded): tid<176 = one (p4, c4) unit ----
    if (tid < 44 * 4) {
        const int p4 = tid >> 2;
        const int l  = tid & 3;
        const int c4 = l << 2;
        float vv[4][4];
        #pragma unroll
        for (int k = 0; k < 4; ++k) {
            int gg = t0 - RMX + 4 * p4 + k;
            if (gg < 0) gg = -gg;
            if (gg >= NT) gg = 2 * NT - 2 - gg;
            const float4 v = *reinterpret_cast<const float4*>(xb + (size_t)gg * NC + c0 + c4);
            vv[k][0] = v.x; vv[k][1] = v.y; vv[k][2] = v.z; vv[k][3] = v.w;
        }
        #pragma unroll
        for (int j = 0; j < 4; ++j) {
            const int kc = (j + l) & 3;
            uint2 pw = {pk2b(vv[0][kc], vv[1][kc]), pk2b(vv[2][kc], vv[3][kc])};
            *reinterpret_cast<uint2*>(&sxT[(c4 + kc) * SXT_LD + 4 * p4]) = pw;
        }
    }
    // ---- stage sxS (f32 [t][c], replicate-left): unit tid, extras on tid 176..235 ----
    {
        const int p = tid >> 2, c4 = (tid & 3) << 2;
        if (p < SXS_ROWS) {
            int gg = t0 - 15 + p; if (gg < 0) gg = 0;
            const float4 v = *reinterpret_cast<const float4*>(xb + (size_t)gg * NC + c0 + c4);
            *reinterpret_cast<float4*>(&sxS[p * SXS_LD + c4]) = v;
        }
        if (tid >= 176 && tid < 236) {
            const int idx2 = 256 + (tid - 176);
            const int p2 = idx2 >> 2, c42 = (idx2 & 3) << 2;
            if (p2 < SXS_ROWS) {
                int gg = t0 - 15 + p2; if (gg < 0) gg = 0;
                const float4 v = *reinterpret_cast<const float4*>(xb + (size_t)gg * NC + c0 + c42);
                *reinterpret_cast<float4*>(&sxS[p2 * SXS_LD + c42]) = v;
            }
        }
    }
    __syncthreads();

    const int lane = tid & 63, wv = tid >> 6;
    const int i16 = lane & 15, g = lane >> 4;
    const int i0 = 16 * wv + 4 * g;

    // ---- causal stats: 19 LDS dwords -> zf, lvf ----
    float zf[4], lvf[4];
    {
        float f[19];
        #pragma unroll
        for (int q = 0; q < 19; ++q) f[q] = sxS[(i0 + q) * SXS_LD + i16];
        float s1 = 0.f, s2 = 0.f;
        #pragma unroll
        for (int q = 0; q < 16; ++q) { const float v = f[q]; s1 += v; s2 = fmaf(v, v, s2); }
        const bool edge = (t0 + i0) < 15;   // only the very first rows need eff<16
        #pragma unroll
        for (int d = 0; d < 4; ++d) {
            float re = 0.0625f;
            if (edge) {
                const int tglob = t0 + i0 + d;
                const float eff = fminf((float)(tglob + 1), 16.0f);
                re = __fdividef(1.0f, eff + 1e-12f);
            }
            const float mn = s1 * re;
            const float m2 = s2 * re;
            const float var = fmaxf(m2 - mn * mn, 0.f);
            zf[d]  = (f[15 + d] - mn) * rsqrtf(var + 1e-6f);
            lvf[d] = __logf(var + 1e-6f);
            if (d < 3) {
                const float ad = f[16 + d], sb = f[d];
                s1 += ad - sb;
                s2 += ad * ad - sb * sb;
            }
        }
    }

    // ---- resolve all 16 blend weights BEFORE the conv (two half-batches) ----
    float wg0[4], wg1[4], wg2[4], wg3[4];
    #pragma unroll
    for (int h = 0; h < 2; ++h) {
        uint4 q0[2], q1[2];
        float az[2], av[2];
        bool fp[2];
        #pragma unroll
        for (int e = 0; e < 2; ++e) {
            const int d = 2 * h + e;
            const int tglob = t0 + i0 + d;
            // t>=15 guarantees |z| <= 15/sqrt(16) = 3.75; lv >= log(1e-6) always
            fp[e] = (!SLOW) && (tglob >= 15) && (fabsf(zf[d]) <= 3.9f) && (lvf[d] <= 3.9f);
            float fz = (zf[d] - ZMINF) * ZSCLF;
            float fv = (lvf[d] - VMINF) * VSCLF;
            fz = fminf(fmaxf(fz, 0.f), 510.0f);
            fv = fminf(fmaxf(fv, 0.f), 254.0f);
            const int zi = (int)fz, vi = (int)fv;
            az[e] = fz - (float)zi;
            av[e] = fv - (float)vi;
            const int cidx = vi * NZ + zi;       // [vi][zi] layout
            if (!SLOW) {
                q0[e] = tb4[cidx];               // corners (zi, vi/vi+1)
                q1[e] = tb4[cidx + 1];           // corners (zi+1, vi/vi+1) -- adjacent
            }
        }
        #pragma unroll
        for (int e = 0; e < 2; ++e) {
            const int d = 2 * h + e;
            if (fp[e]) {
                const _Float16 avh = (_Float16)av[e], azh = (_Float16)az[e];
                const h2v av2 = {avh, avh}, az2 = {azh, azh};
                const h2v p00 = u2h(q0[e].x), p01 = u2h(q0[e].y);
                const h2v p10 = u2h(q0[e].z), p11 = u2h(q0[e].w);
                const h2v s00 = u2h(q1[e].x), s01 = u2h(q1[e].y);
                const h2v s10 = u2h(q1[e].z), s11 = u2h(q1[e].w);
                const h2v r0a = p00 + av2 * (p10 - p00);   // w0,w1 @ zi
                const h2v r0b = p01 + av2 * (p11 - p01);   // w2,w3 @ zi
                const h2v r1a = s00 + av2 * (s10 - s00);   // w0,w1 @ zi+1
                const h2v r1b = s01 + av2 * (s11 - s01);   // w2,w3 @ zi+1
                const h2v wa = r0a + az2 * (r1a - r0a);
                const h2v wb = r0b + az2 * (r1b - r0b);
                wg0[d] = (float)wa[0]; wg1[d] = (float)wa[1];
                wg2[d] = (float)wb[0]; wg3[d] = (float)wb[1];
            } else {
                float wv5[5];
                mlp_w_fast(zf[d], lvf[d], W1, b1, W2, b2, wv5);
                wg0[d] = wv5[0]; wg1[d] = wv5[1]; wg2[d] = wv5[2]; wg3[d] = wv5[3];
            }
        }
    }

    // ---- conv via MFMA: 13 k-steps over 5 sigmas ----
    const int fbase[NS] = {0, 2, 4, 6, 9};
    const int ksn[NS]   = {2, 2, 2, 3, 4};
    const int RA[NS]    = {16, 16, 24, 40, 56};
    f32x4 acc[NS];
    #pragma unroll
    for (int s = 0; s < NS; ++s) acc[s] = (f32x4){0.f, 0.f, 0.f, 0.f};
    #pragma unroll
    for (int s = 0; s < NS; ++s) {
        #pragma unroll
        for (int kk = 0; kk < ksn[s]; ++kk) {
            const bf16x8 A = *reinterpret_cast<const bf16x8*>(&afr4[(fbase[s] + kk) * 64 + lane]);
            const int tof = 16 * wv - RA[s] + 32 * kk + RMX + 8 * g;
            const bf16x8 B = *reinterpret_cast<const bf16x8*>(&sxT[i16 * SXT_LD + tof]);
            acc[s] = __builtin_amdgcn_mfma_f32_16x16x32_bf16(A, B, acc[s], 0, 0, 0);
        }
    }

    // ---- blend + store ----
    const int c = c0 + i16;
    #pragma unroll
    for (int d = 0; d < 4; ++d) {
        const int tglob = t0 + i0 + d;
        const float y4 = acc[4][d];
        float res = y4;
        res = fmaf(wg0[d], acc[0][d] - y4, res);
        res = fmaf(wg1[d], acc[1][d] - y4, res);
        res = fmaf(wg2[d], acc[2][d] - y4, res);
        res = fmaf(wg3[d], acc[3][d] - y4, res);
        out[((size_t)b * NT + tglob) * NC + c] = res;
    }
}

extern "C" void kernel_launch(void* const* d_in, const int* in_sizes, int n_in,
                              void* d_out, int out_size, void* d_ws, size_t ws_size,
                              hipStream_t stream) {
    const float* x  = (const float*)d_in[0];
    const float* W1 = (const float*)d_in[1];
    const float* b1 = (const float*)d_in[2];
    const float* W2 = (const float*)d_in[3];
    const float* b2 = (const float*)d_in[4];
    float* out = (float*)d_out;
    unsigned short* afr = (unsigned short*)d_ws;              // 13312 B used
    unsigned int* tbl = (unsigned int*)((char*)d_ws + FRAG_BYTES);
    const int build_tbl = (ws_size >= WS_NEED) ? 1 : 0;

    init_all_kernel<<<1 + (NZ * NV) / 256, 256, 0, stream>>>(W1, b1, W2, b2, afr, tbl, build_tbl);
    if (build_tbl) {
        fused9_kernel<false><<<4 * NB * (NT / TTILE), 256, 0, stream>>>(
            x, W1, b1, W2, b2, (const uint4*)afr, (const uint4*)tbl, out);
    } else {
        fused9_kernel<true><<<4 * NB * (NT / TTILE), 256, 0, stream>>>(
            x, W1, b1, W2, b2, (const uint4*)afr, (const uint4*)tbl, out);
    }
}